// Round 1
// baseline (279.803 us; speedup 1.0000x reference)
//
#include <hip/hip_runtime.h>

#define SEQ 2048
#define DMODEL 2048

typedef __attribute__((ext_vector_type(8))) _Float16 half8;
typedef __attribute__((ext_vector_type(4))) float f32x4;

typedef const __attribute__((address_space(1))) void* gptr_t;
typedef __attribute__((address_space(3))) void* lptr_t;

static __device__ __forceinline__ void gload16(const void* g, void* l) {
  __builtin_amdgcn_global_load_lds((gptr_t)g, (lptr_t)l, 16, 0, 0);
}

static __device__ __forceinline__ unsigned short f2h(float f) {
  _Float16 h = (_Float16)f;
  union { _Float16 h; unsigned short u; } v; v.h = h;
  return v.u;
}

// ---------------- elementwise fp32 -> fp16 ----------------
__global__ void k_cvt(const float* __restrict__ in, unsigned short* __restrict__ out, int n) {
  int i = (blockIdx.x * 256 + threadIdx.x) * 4;
  if (i >= n) return;
  float4 v = *(const float4*)(in + i);
  ushort4 o;
  o.x = f2h(v.x); o.y = f2h(v.y); o.z = f2h(v.z); o.w = f2h(v.w);
  *(ushort4*)(out + i) = o;
}

// ---------------- tiled transpose + convert: in fp32 [K][N] (row stride ldin) -> out fp16 [N][K] ----------------
__global__ void k_tcvt(const float* __restrict__ in, unsigned short* __restrict__ out,
                       int K, int N, int ldin, long inb, long outb) {
  in += (long)blockIdx.z * inb;
  out += (long)blockIdx.z * outb;
  __shared__ float tile[32][33];
  int n0 = blockIdx.x * 32, k0 = blockIdx.y * 32;
  int tx = threadIdx.x, ty = threadIdx.y;  // 32 x 8
  #pragma unroll
  for (int j = ty; j < 32; j += 8)
    tile[j][tx] = in[(long)(k0 + j) * ldin + n0 + tx];
  __syncthreads();
  #pragma unroll
  for (int j = ty; j < 32; j += 8)
    out[(long)(n0 + j) * K + k0 + tx] = f2h(tile[tx][j]);
}

// ---------------- GEMM: C[M][N] fp32 = A[M][K] fp16 * Bt[N][K] fp16 ----------------
// 128x128 tile, BK=32, 4 waves (2x2), each wave 64x64 via 4x4 16x16x32 MFMA frags.
__global__ __launch_bounds__(256) void k_gemm(const unsigned short* __restrict__ A,
                                              const unsigned short* __restrict__ B,
                                              float* __restrict__ C, int M, int N, int K) {
  __shared__ unsigned short As[128 * 32];
  __shared__ unsigned short Bs[128 * 32];
  int t = threadIdx.x;
  int l = t & 63;
  int w = t >> 6;
  int wm = w >> 1, wn = w & 1;
  int lr = l & 15, lh = l >> 4;
  long m0 = (long)blockIdx.y * 128, n0 = (long)blockIdx.x * 128;

  const unsigned short* Ag = A + (m0 + (t >> 2)) * K + (t & 3) * 8;
  const unsigned short* Bg = B + (n0 + (t >> 2)) * K + (t & 3) * 8;
  unsigned short* Asl = As + t * 8;
  unsigned short* Bsl = Bs + t * 8;

  f32x4 acc[4][4];
  #pragma unroll
  for (int i = 0; i < 4; i++)
    #pragma unroll
    for (int j = 0; j < 4; j++)
      acc[i][j] = (f32x4){0.f, 0.f, 0.f, 0.f};

  for (int k0 = 0; k0 < K; k0 += 32) {
    __syncthreads();
    gload16(Ag + k0, Asl);
    gload16(Ag + 64 * K + k0, Asl + 64 * 32);
    gload16(Bg + k0, Bsl);
    gload16(Bg + 64 * K + k0, Bsl + 64 * 32);
    __syncthreads();
    half8 a[4], b[4];
    #pragma unroll
    for (int mf = 0; mf < 4; mf++)
      a[mf] = *(const half8*)&As[(wm * 64 + mf * 16 + lr) * 32 + lh * 8];
    #pragma unroll
    for (int nf = 0; nf < 4; nf++)
      b[nf] = *(const half8*)&Bs[(wn * 64 + nf * 16 + lr) * 32 + lh * 8];
    #pragma unroll
    for (int mf = 0; mf < 4; mf++)
      #pragma unroll
      for (int nf = 0; nf < 4; nf++)
        acc[mf][nf] = __builtin_amdgcn_mfma_f32_16x16x32_f16(a[mf], b[nf], acc[mf][nf], 0, 0, 0);
  }

  #pragma unroll
  for (int mf = 0; mf < 4; mf++)
    #pragma unroll
    for (int nf = 0; nf < 4; nf++)
      #pragma unroll
      for (int i = 0; i < 4; i++)
        C[(m0 + wm * 64 + mf * 16 + lh * 4 + i) * N + n0 + wn * 64 + nf * 16 + lr] = acc[mf][nf][i];
}

// ---------------- RoPE on Q and K regions of QKV fp32 [S][3072] -> Qr fp16 [S][2048], Kr fp16 [8][S][64] ----------------
__global__ void k_rope(const float* __restrict__ QKV, const float* __restrict__ fc,
                       const float* __restrict__ fs, unsigned short* __restrict__ Qr,
                       unsigned short* __restrict__ Kr) {
  int s = blockIdx.x;
  for (int p = threadIdx.x; p < 1280; p += 256) {
    int col = p * 2;
    float t0 = QKV[(long)s * 3072 + col];
    float t1 = QKV[(long)s * 3072 + col + 1];
    if (col < 2048) {
      int j = (col & 63) >> 1;
      float c = fc[s * 32 + j], sn = fs[s * 32 + j];
      Qr[(long)s * 2048 + col] = f2h(t0 * c - t1 * sn);
      Qr[(long)s * 2048 + col + 1] = f2h(t0 * sn + t1 * c);
    } else {
      int cc = col - 2048;
      int hk = cc >> 6, d = cc & 63, j = d >> 1;
      float c = fc[s * 32 + j], sn = fs[s * 32 + j];
      Kr[((long)hk * SEQ + s) * 64 + d] = f2h(t0 * c - t1 * sn);
      Kr[((long)hk * SEQ + s) * 64 + d + 1] = f2h(t0 * sn + t1 * c);
    }
  }
}

// ---------------- causal GQA flash attention ----------------
// grid (S/128, 32 heads), 256 threads = 4 independent waves, each wave 32 q-rows.
// Qr [S][2048] fp16, Kr [8][S][64] fp16, Vt [8][64][S] fp16, AO [S][2048] fp16.
__global__ __launch_bounds__(256) void k_attn(const unsigned short* __restrict__ Qr,
                                              const unsigned short* __restrict__ Kr,
                                              const unsigned short* __restrict__ Vt,
                                              unsigned short* __restrict__ AO) {
  __shared__ unsigned short Plds[4][32 * 40];
  int t = threadIdx.x;
  int w = t >> 6, l = t & 63;
  int lr = l & 15, lh = l >> 4;
  int h = blockIdx.y, hkv = h >> 2;
  int q0 = blockIdx.x * 128 + w * 32;

  // Q fragments hoisted (2 m-frags x 2 k-steps)
  half8 Qf[2][2];
  #pragma unroll
  for (int m = 0; m < 2; m++)
    #pragma unroll
    for (int kk = 0; kk < 2; kk++)
      Qf[m][kk] = *(const half8*)&Qr[(long)(q0 + m * 16 + lr) * 2048 + h * 64 + kk * 32 + lh * 8];

  f32x4 O[2][4];
  #pragma unroll
  for (int m = 0; m < 2; m++)
    #pragma unroll
    for (int n = 0; n < 4; n++)
      O[m][n] = (f32x4){0.f, 0.f, 0.f, 0.f};
  float mrun[2][4], lrun[2][4];
  #pragma unroll
  for (int m = 0; m < 2; m++)
    #pragma unroll
    for (int i = 0; i < 4; i++) { mrun[m][i] = -1e30f; lrun[m][i] = 0.f; }

  const unsigned short* Kh = Kr + (long)hkv * SEQ * 64;
  const unsigned short* Vh = Vt + (long)hkv * 64 * SEQ;
  unsigned short* Pw = Plds[w];

  for (int t0 = 0; t0 <= q0; t0 += 32) {
    half8 Kf[2][2];
    #pragma unroll
    for (int n = 0; n < 2; n++)
      #pragma unroll
      for (int kk = 0; kk < 2; kk++)
        Kf[n][kk] = *(const half8*)&Kh[(long)(t0 + n * 16 + lr) * 64 + kk * 32 + lh * 8];

    f32x4 Sc[2][2];
    #pragma unroll
    for (int m = 0; m < 2; m++)
      #pragma unroll
      for (int n = 0; n < 2; n++)
        Sc[m][n] = (f32x4){0.f, 0.f, 0.f, 0.f};
    #pragma unroll
    for (int m = 0; m < 2; m++)
      #pragma unroll
      for (int n = 0; n < 2; n++)
        #pragma unroll
        for (int kk = 0; kk < 2; kk++)
          Sc[m][n] = __builtin_amdgcn_mfma_f32_16x16x32_f16(Qf[m][kk], Kf[n][kk], Sc[m][n], 0, 0, 0);

    bool diag = (t0 == q0);
    float P[2][2][4];
    #pragma unroll
    for (int m = 0; m < 2; m++) {
      float fac[4];
      #pragma unroll
      for (int i = 0; i < 4; i++) {
        float s0 = Sc[m][0][i] * 0.125f;
        float s1 = Sc[m][1][i] * 0.125f;
        if (diag) {
          int r = m * 16 + lh * 4 + i;
          if (lr > r) s0 = -1e30f;
          if (16 + lr > r) s1 = -1e30f;
        }
        float mx = fmaxf(s0, s1);
        mx = fmaxf(mx, __shfl_xor(mx, 1));
        mx = fmaxf(mx, __shfl_xor(mx, 2));
        mx = fmaxf(mx, __shfl_xor(mx, 4));
        mx = fmaxf(mx, __shfl_xor(mx, 8));
        float nm = fmaxf(mrun[m][i], mx);
        float f = __expf(mrun[m][i] - nm);
        float p0 = __expf(s0 - nm);
        float p1 = __expf(s1 - nm);
        float ts = p0 + p1;
        ts += __shfl_xor(ts, 1);
        ts += __shfl_xor(ts, 2);
        ts += __shfl_xor(ts, 4);
        ts += __shfl_xor(ts, 8);
        mrun[m][i] = nm;
        lrun[m][i] = lrun[m][i] * f + ts;
        fac[i] = f;
        P[m][0][i] = p0;
        P[m][1][i] = p1;
      }
      #pragma unroll
      for (int n = 0; n < 4; n++)
        #pragma unroll
        for (int i = 0; i < 4; i++)
          O[m][n][i] *= fac[i];
    }

    // P -> wave-private LDS (C-layout) then re-read as A-fragments
    #pragma unroll
    for (int m = 0; m < 2; m++)
      #pragma unroll
      for (int n = 0; n < 2; n++)
        #pragma unroll
        for (int i = 0; i < 4; i++)
          Pw[(m * 16 + lh * 4 + i) * 40 + n * 16 + lr] = f2h(P[m][n][i]);
    asm volatile("" ::: "memory");  // keep ds_write before ds_read (same-wave LDS is in-order)
    half8 Pf[2];
    #pragma unroll
    for (int m = 0; m < 2; m++)
      Pf[m] = *(const half8*)&Pw[(m * 16 + lr) * 40 + lh * 8];

    half8 Vf[4];
    #pragma unroll
    for (int n = 0; n < 4; n++)
      Vf[n] = *(const half8*)&Vh[(long)(n * 16 + lr) * SEQ + t0 + lh * 8];

    #pragma unroll
    for (int m = 0; m < 2; m++)
      #pragma unroll
      for (int n = 0; n < 4; n++)
        O[m][n] = __builtin_amdgcn_mfma_f32_16x16x32_f16(Pf[m], Vf[n], O[m][n], 0, 0, 0);
  }

  #pragma unroll
  for (int m = 0; m < 2; m++) {
    float inv[4];
    #pragma unroll
    for (int i = 0; i < 4; i++) inv[i] = 1.f / lrun[m][i];
    #pragma unroll
    for (int n = 0; n < 4; n++)
      #pragma unroll
      for (int i = 0; i < 4; i++)
        AO[(long)(q0 + m * 16 + lh * 4 + i) * 2048 + h * 64 + n * 16 + lr] = f2h(O[m][n][i] * inv[i]);
  }
}

extern "C" void kernel_launch(void* const* d_in, const int* in_sizes, int n_in,
                              void* d_out, int out_size, void* d_ws, size_t ws_size,
                              hipStream_t stream) {
  const float* x  = (const float*)d_in[0];
  const float* fc = (const float*)d_in[1];
  const float* fs = (const float*)d_in[2];
  // d_in[3] causal_mask: implemented analytically (values are exactly 0 / -1e9)
  const float* Wq = (const float*)d_in[4];
  const float* Wk = (const float*)d_in[5];
  const float* Wv = (const float*)d_in[6];
  const float* Wo = (const float*)d_in[7];
  float* out = (float*)d_out;

  char* ws = (char*)d_ws;
  unsigned short* xb  = (unsigned short*)(ws);                  // 8 MB (reused as AO later)
  unsigned short* WT  = (unsigned short*)(ws + (8l  << 20));    // 12 MB  [3072][2048] fp16 (Wq^T|Wk^T|Wv^T)
  unsigned short* WoT = (unsigned short*)(ws + (20l << 20));    // 8 MB   [2048][2048] fp16
  float*          QKV = (float*)(ws + (28l << 20));             // 24 MB  [2048][3072] fp32
  unsigned short* Qr  = (unsigned short*)(ws + (52l << 20));    // 8 MB
  unsigned short* Kr  = (unsigned short*)(ws + (60l << 20));    // 2 MB
  unsigned short* Vt  = (unsigned short*)(ws + (62l << 20));    // 2 MB
  unsigned short* AO  = xb;                                     // overlay: xb dead after QKV GEMM

  dim3 tb(32, 8);
  k_cvt<<<4096, 256, 0, stream>>>(x, xb, 2048 * 2048);
  k_tcvt<<<dim3(64, 64, 1), tb, 0, stream>>>(Wq, WT, 2048, 2048, 2048, 0, 0);
  k_tcvt<<<dim3(16, 64, 1), tb, 0, stream>>>(Wk, WT + 2048l * 2048, 2048, 512, 512, 0, 0);
  k_tcvt<<<dim3(16, 64, 1), tb, 0, stream>>>(Wv, WT + 2560l * 2048, 2048, 512, 512, 0, 0);
  k_tcvt<<<dim3(64, 64, 1), tb, 0, stream>>>(Wo, WoT, 2048, 2048, 2048, 0, 0);

  k_gemm<<<dim3(24, 16), 256, 0, stream>>>(xb, WT, QKV, 2048, 3072, 2048);

  k_rope<<<2048, 256, 0, stream>>>(QKV, fc, fs, Qr, Kr);
  // V^T per head: QKV cols [2560 + h*64, +64) (fp32) -> Vt[h][64][2048] fp16
  k_tcvt<<<dim3(2, 64, 8), tb, 0, stream>>>(QKV + 2560, Vt, 2048, 64, 3072, 64, 64l * 2048);

  k_attn<<<dim3(16, 32), 256, 0, stream>>>(Qr, Kr, Vt, AO);

  k_gemm<<<dim3(16, 16), 256, 0, stream>>>(AO, WoT, out, 2048, 2048, 2048);
}

// Round 3
// 224.449 us; speedup vs baseline: 1.2466x; 1.2466x over previous
//
#include <hip/hip_runtime.h>

#define SEQ 2048
#define DMODEL 2048

typedef __attribute__((ext_vector_type(8))) _Float16 half8;
typedef __attribute__((ext_vector_type(4))) float f32x4;

typedef const __attribute__((address_space(1))) void* gptr_t;
typedef __attribute__((address_space(3))) void* lptr_t;

static __device__ __forceinline__ void gload16(const void* g, void* l) {
  __builtin_amdgcn_global_load_lds((gptr_t)g, (lptr_t)l, 16, 0, 0);
}

static __device__ __forceinline__ unsigned short f2h(float f) {
  _Float16 h = (_Float16)f;
  union { _Float16 h; unsigned short u; } v; v.h = h;
  return v.u;
}

static __device__ __forceinline__ unsigned int pkh2(float a, float b) {
  union { __fp16 __attribute__((ext_vector_type(2))) h; unsigned int u; } v;
  v.h = __builtin_amdgcn_cvt_pkrtz(a, b);
  return v.u;
}

// ---------------- elementwise fp32 -> fp16 ----------------
__global__ void k_cvt(const float* __restrict__ in, unsigned short* __restrict__ out, int n) {
  int i = (blockIdx.x * 256 + threadIdx.x) * 4;
  if (i >= n) return;
  float4 v = *(const float4*)(in + i);
  ushort4 o;
  o.x = f2h(v.x); o.y = f2h(v.y); o.z = f2h(v.z); o.w = f2h(v.w);
  *(ushort4*)(out + i) = o;
}

// ---------------- tiled transpose + convert: in fp32 [K][N] (row stride ldin) -> out fp16 [N][K] ----------------
__global__ void k_tcvt(const float* __restrict__ in, unsigned short* __restrict__ out,
                       int K, int N, int ldin, long inb, long outb) {
  in += (long)blockIdx.z * inb;
  out += (long)blockIdx.z * outb;
  __shared__ float tile[32][33];
  int n0 = blockIdx.x * 32, k0 = blockIdx.y * 32;
  int tx = threadIdx.x, ty = threadIdx.y;  // 32 x 8
  #pragma unroll
  for (int j = ty; j < 32; j += 8)
    tile[j][tx] = in[(long)(k0 + j) * ldin + n0 + tx];
  __syncthreads();
  #pragma unroll
  for (int j = ty; j < 32; j += 8)
    out[(long)(n0 + j) * K + k0 + tx] = f2h(tile[tx][j]);
}

// ---------------- GEMM: C[M][N] fp32 = A[M][K] fp16 * Bt[N][K] fp16 ----------------
__global__ __launch_bounds__(256) void k_gemm(const unsigned short* __restrict__ A,
                                              const unsigned short* __restrict__ B,
                                              float* __restrict__ C, int M, int N, int K) {
  __shared__ unsigned short As[128 * 32];
  __shared__ unsigned short Bs[128 * 32];
  int t = threadIdx.x;
  int l = t & 63;
  int w = t >> 6;
  int wm = w >> 1, wn = w & 1;
  int lr = l & 15, lh = l >> 4;
  long m0 = (long)blockIdx.y * 128, n0 = (long)blockIdx.x * 128;

  const unsigned short* Ag = A + (m0 + (t >> 2)) * K + (t & 3) * 8;
  const unsigned short* Bg = B + (n0 + (t >> 2)) * K + (t & 3) * 8;
  unsigned short* Asl = As + t * 8;
  unsigned short* Bsl = Bs + t * 8;

  f32x4 acc[4][4];
  #pragma unroll
  for (int i = 0; i < 4; i++)
    #pragma unroll
    for (int j = 0; j < 4; j++)
      acc[i][j] = (f32x4){0.f, 0.f, 0.f, 0.f};

  for (int k0 = 0; k0 < K; k0 += 32) {
    __syncthreads();
    gload16(Ag + k0, Asl);
    gload16(Ag + 64 * K + k0, Asl + 64 * 32);
    gload16(Bg + k0, Bsl);
    gload16(Bg + 64 * K + k0, Bsl + 64 * 32);
    __syncthreads();
    half8 a[4], b[4];
    #pragma unroll
    for (int mf = 0; mf < 4; mf++)
      a[mf] = *(const half8*)&As[(wm * 64 + mf * 16 + lr) * 32 + lh * 8];
    #pragma unroll
    for (int nf = 0; nf < 4; nf++)
      b[nf] = *(const half8*)&Bs[(wn * 64 + nf * 16 + lr) * 32 + lh * 8];
    #pragma unroll
    for (int mf = 0; mf < 4; mf++)
      #pragma unroll
      for (int nf = 0; nf < 4; nf++)
        acc[mf][nf] = __builtin_amdgcn_mfma_f32_16x16x32_f16(a[mf], b[nf], acc[mf][nf], 0, 0, 0);
  }

  #pragma unroll
  for (int mf = 0; mf < 4; mf++)
    #pragma unroll
    for (int nf = 0; nf < 4; nf++)
      #pragma unroll
      for (int i = 0; i < 4; i++)
        C[(m0 + wm * 64 + mf * 16 + lh * 4 + i) * N + n0 + wn * 64 + nf * 16 + lr] = acc[mf][nf][i];
}

// ---------------- RoPE ----------------
__global__ void k_rope(const float* __restrict__ QKV, const float* __restrict__ fc,
                       const float* __restrict__ fs, unsigned short* __restrict__ Qr,
                       unsigned short* __restrict__ Kr) {
  int s = blockIdx.x;
  for (int p = threadIdx.x; p < 1280; p += 256) {
    int col = p * 2;
    float t0 = QKV[(long)s * 3072 + col];
    float t1 = QKV[(long)s * 3072 + col + 1];
    if (col < 2048) {
      int j = (col & 63) >> 1;
      float c = fc[s * 32 + j], sn = fs[s * 32 + j];
      Qr[(long)s * 2048 + col] = f2h(t0 * c - t1 * sn);
      Qr[(long)s * 2048 + col + 1] = f2h(t0 * sn + t1 * c);
    } else {
      int cc = col - 2048;
      int hk = cc >> 6, d = cc & 63, j = d >> 1;
      float c = fc[s * 32 + j], sn = fs[s * 32 + j];
      Kr[((long)hk * SEQ + s) * 64 + d] = f2h(t0 * c - t1 * sn);
      Kr[((long)hk * SEQ + s) * 64 + d + 1] = f2h(t0 * sn + t1 * c);
    }
  }
}

// ---------------- causal GQA flash attention, swapped-QK^T, 1 wave / 32 q-rows ----------------
// grid (32 heads, 64 q-tiles rev), block 64.
// Qr [S][2048] fp16, Kr [8][S][64] fp16, Vt [8][64][S] fp16, AO [S][2048] fp16.
__global__ __launch_bounds__(64) void k_attn(const unsigned short* __restrict__ Qr,
                                             const unsigned short* __restrict__ Kr,
                                             const unsigned short* __restrict__ Vt,
                                             unsigned short* __restrict__ AO) {
  __shared__ unsigned short Pq[32 * 40];  // [32 q][32 key, pad to 40]
  int l = threadIdx.x;
  int lr = l & 15, lh = l >> 4;
  int h = blockIdx.x, hkv = h >> 2;
  int q0 = (gridDim.y - 1 - blockIdx.y) * 32;  // longest blocks dispatch first

  // Q fragments hoisted: B-operand of swapped QK^T (identical addresses to A-operand of normal)
  half8 Qf[2][2];
  #pragma unroll
  for (int m = 0; m < 2; m++)
    #pragma unroll
    for (int kk = 0; kk < 2; kk++)
      Qf[m][kk] = *(const half8*)&Qr[(long)(q0 + m * 16 + lr) * 2048 + h * 64 + kk * 32 + lh * 8];

  f32x4 O[2][4];
  #pragma unroll
  for (int m = 0; m < 2; m++)
    #pragma unroll
    for (int n = 0; n < 4; n++)
      O[m][n] = (f32x4){0.f, 0.f, 0.f, 0.f};
  float mrun[2] = {-1e30f, -1e30f};
  float lrun[2] = {0.f, 0.f};

  const unsigned short* Kh = Kr + (long)hkv * SEQ * 64;
  const unsigned short* Vh = Vt + (long)hkv * 64 * SEQ;
  const float SC = 0.125f * 1.44269504f;  // 1/sqrt(64) * log2(e)

  for (int t0 = 0; t0 <= q0; t0 += 32) {
    // K fragments: A-operand of swapped QK^T
    half8 Kf[2][2];
    #pragma unroll
    for (int n = 0; n < 2; n++)
      #pragma unroll
      for (int kk = 0; kk < 2; kk++)
        Kf[n][kk] = *(const half8*)&Kh[(long)(t0 + n * 16 + lr) * 64 + kk * 32 + lh * 8];

    // St[n][m] = S^T tile: lane holds key = t0+16n+4lh+i, q = q0+16m+lr
    f32x4 St[2][2];
    #pragma unroll
    for (int n = 0; n < 2; n++)
      #pragma unroll
      for (int m = 0; m < 2; m++)
        St[n][m] = (f32x4){0.f, 0.f, 0.f, 0.f};
    #pragma unroll
    for (int n = 0; n < 2; n++)
      #pragma unroll
      for (int m = 0; m < 2; m++)
        #pragma unroll
        for (int kk = 0; kk < 2; kk++)
          St[n][m] = __builtin_amdgcn_mfma_f32_16x16x32_f16(Kf[n][kk], Qf[m][kk], St[n][m], 0, 0, 0);

    // V fragments (issue early to overlap with softmax)
    half8 Vf[4];
    #pragma unroll
    for (int nf = 0; nf < 4; nf++)
      Vf[nf] = *(const half8*)&Vh[(long)(nf * 16 + lr) * SEQ + t0 + lh * 8];

    bool diag = (t0 == q0);
    float fac[2];
    #pragma unroll
    for (int m = 0; m < 2; m++) {
      float s[2][4];
      float mx = -1e30f;
      #pragma unroll
      for (int n = 0; n < 2; n++)
        #pragma unroll
        for (int i = 0; i < 4; i++) {
          float v = St[n][m][i] * SC;
          if (diag && (16 * n + 4 * lh + i > 16 * m + lr)) v = -1e30f;
          s[n][i] = v;
          mx = fmaxf(mx, v);
        }
      mx = fmaxf(mx, __shfl_xor(mx, 16));
      mx = fmaxf(mx, __shfl_xor(mx, 32));
      float nm = fmaxf(mrun[m], mx);
      float f = __builtin_exp2f(mrun[m] - nm);
      float ts = 0.f;
      float p[2][4];
      #pragma unroll
      for (int n = 0; n < 2; n++)
        #pragma unroll
        for (int i = 0; i < 4; i++) {
          p[n][i] = __builtin_exp2f(s[n][i] - nm);
          ts += p[n][i];
        }
      ts += __shfl_xor(ts, 16);
      ts += __shfl_xor(ts, 32);
      mrun[m] = nm;
      lrun[m] = lrun[m] * f + ts;
      fac[m] = f;

      // pack P^T -> LDS [q][key]: lane writes keys 16n+4lh..+3 of row q=16m+lr
      #pragma unroll
      for (int n = 0; n < 2; n++) {
        uint2 val;
        val.x = pkh2(p[n][0], p[n][1]);
        val.y = pkh2(p[n][2], p[n][3]);
        *(uint2*)&Pq[(16 * m + lr) * 40 + 16 * n + 4 * lh] = val;
      }
    }

    // O rescale: lane's O rows are q = 16m+4lh+i, fac lives at lane lr=q
    #pragma unroll
    for (int m = 0; m < 2; m++)
      #pragma unroll
      for (int i = 0; i < 4; i++) {
        float fi = __shfl(fac[m], 4 * lh + i);
        #pragma unroll
        for (int n = 0; n < 4; n++)
          O[m][n][i] *= fi;
      }

    asm volatile("" ::: "memory");  // order ds_write before ds_read (same wave)

    // read P as PV A-fragments: lane holds P[q=16m+lr][k=8lh..+7]
    half8 Pf[2];
    #pragma unroll
    for (int m = 0; m < 2; m++)
      Pf[m] = *(const half8*)&Pq[(16 * m + lr) * 40 + lh * 8];

    #pragma unroll
    for (int m = 0; m < 2; m++)
      #pragma unroll
      for (int nf = 0; nf < 4; nf++)
        O[m][nf] = __builtin_amdgcn_mfma_f32_16x16x32_f16(Pf[m], Vf[nf], O[m][nf], 0, 0, 0);
  }

  #pragma unroll
  for (int m = 0; m < 2; m++) {
    float rinv = 1.f / lrun[m];
    #pragma unroll
    for (int i = 0; i < 4; i++) {
      float vi = __shfl(rinv, 4 * lh + i);
      #pragma unroll
      for (int n = 0; n < 4; n++)
        AO[(long)(q0 + m * 16 + lh * 4 + i) * 2048 + h * 64 + n * 16 + lr] = f2h(O[m][n][i] * vi);
    }
  }
}

extern "C" void kernel_launch(void* const* d_in, const int* in_sizes, int n_in,
                              void* d_out, int out_size, void* d_ws, size_t ws_size,
                              hipStream_t stream) {
  const float* x  = (const float*)d_in[0];
  const float* fc = (const float*)d_in[1];
  const float* fs = (const float*)d_in[2];
  const float* Wq = (const float*)d_in[4];
  const float* Wk = (const float*)d_in[5];
  const float* Wv = (const float*)d_in[6];
  const float* Wo = (const float*)d_in[7];
  float* out = (float*)d_out;

  char* ws = (char*)d_ws;
  unsigned short* xb  = (unsigned short*)(ws);                  // 8 MB (reused as AO later)
  unsigned short* WT  = (unsigned short*)(ws + (8l  << 20));    // 12 MB  [3072][2048] fp16
  unsigned short* WoT = (unsigned short*)(ws + (20l << 20));    // 8 MB   [2048][2048] fp16
  float*          QKV = (float*)(ws + (28l << 20));             // 24 MB  [2048][3072] fp32
  unsigned short* Qr  = (unsigned short*)(ws + (52l << 20));    // 8 MB
  unsigned short* Kr  = (unsigned short*)(ws + (60l << 20));    // 2 MB
  unsigned short* Vt  = (unsigned short*)(ws + (62l << 20));    // 2 MB
  unsigned short* AO  = xb;                                     // overlay: xb dead after QKV GEMM

  dim3 tb(32, 8);
  k_cvt<<<4096, 256, 0, stream>>>(x, xb, 2048 * 2048);
  k_tcvt<<<dim3(64, 64, 1), tb, 0, stream>>>(Wq, WT, 2048, 2048, 2048, 0, 0);
  k_tcvt<<<dim3(16, 64, 1), tb, 0, stream>>>(Wk, WT + 2048l * 2048, 2048, 512, 512, 0, 0);
  k_tcvt<<<dim3(16, 64, 1), tb, 0, stream>>>(Wv, WT + 2560l * 2048, 2048, 512, 512, 0, 0);
  k_tcvt<<<dim3(64, 64, 1), tb, 0, stream>>>(Wo, WoT, 2048, 2048, 2048, 0, 0);

  k_gemm<<<dim3(24, 16), 256, 0, stream>>>(xb, WT, QKV, 2048, 3072, 2048);

  k_rope<<<2048, 256, 0, stream>>>(QKV, fc, fs, Qr, Kr);
  k_tcvt<<<dim3(2, 64, 8), tb, 0, stream>>>(QKV + 2560, Vt, 2048, 64, 3072, 64, 64l * 2048);

  k_attn<<<dim3(32, 64), 64, 0, stream>>>(Qr, Kr, Vt, AO);

  k_gemm<<<dim3(16, 16), 256, 0, stream>>>(AO, WoT, out, 2048, 2048, 2048);
}

// Round 4
// 213.895 us; speedup vs baseline: 1.3081x; 1.0493x over previous
//
#include <hip/hip_runtime.h>

#define SEQ 2048
#define DMODEL 2048

typedef __attribute__((ext_vector_type(8))) _Float16 half8;
typedef __attribute__((ext_vector_type(4))) float f32x4;

typedef const __attribute__((address_space(1))) void* gptr_t;
typedef __attribute__((address_space(3))) void* lptr_t;

static __device__ __forceinline__ void gload16(const void* g, void* l) {
  __builtin_amdgcn_global_load_lds((gptr_t)g, (lptr_t)l, 16, 0, 0);
}

static __device__ __forceinline__ unsigned short f2h(float f) {
  _Float16 h = (_Float16)f;
  union { _Float16 h; unsigned short u; } v; v.h = h;
  return v.u;
}

static __device__ __forceinline__ unsigned int pkh2(float a, float b) {
  union { __fp16 __attribute__((ext_vector_type(2))) h; unsigned int u; } v;
  v.h = __builtin_amdgcn_cvt_pkrtz(a, b);
  return v.u;
}

// ---------------- elementwise fp32 -> fp16 ----------------
__global__ void k_cvt(const float* __restrict__ in, unsigned short* __restrict__ out, int n) {
  int i = (blockIdx.x * 256 + threadIdx.x) * 4;
  if (i >= n) return;
  float4 v = *(const float4*)(in + i);
  ushort4 o;
  o.x = f2h(v.x); o.y = f2h(v.y); o.z = f2h(v.z); o.w = f2h(v.w);
  *(ushort4*)(out + i) = o;
}

// ---------------- tiled transpose + convert: in fp32 [K][N] -> out fp16 [N][K] ----------------
__global__ void k_tcvt(const float* __restrict__ in, unsigned short* __restrict__ out,
                       int K, int N, int ldin, long inb, long outb) {
  in += (long)blockIdx.z * inb;
  out += (long)blockIdx.z * outb;
  __shared__ float tile[32][33];
  int n0 = blockIdx.x * 32, k0 = blockIdx.y * 32;
  int tx = threadIdx.x, ty = threadIdx.y;  // 32 x 8
  #pragma unroll
  for (int j = ty; j < 32; j += 8)
    tile[j][tx] = in[(long)(k0 + j) * ldin + n0 + tx];
  __syncthreads();
  #pragma unroll
  for (int j = ty; j < 32; j += 8)
    out[(long)(n0 + j) * K + k0 + tx] = f2h(tile[tx][j]);
}

// ---------------- GEMM: C[M][N] fp32 = A[M][K] fp16 * Bt[N][K] fp16 ----------------
// 128x128 tile, BK=32, depth-2 pipelined 3-buffer ring with counted vmcnt (T3+T4 minimum).
__global__ __launch_bounds__(256) void k_gemm(const unsigned short* __restrict__ A,
                                              const unsigned short* __restrict__ B,
                                              float* __restrict__ C, int M, int N, int K) {
  __shared__ unsigned short As[3 * 4096];
  __shared__ unsigned short Bs[3 * 4096];
  int t = threadIdx.x;
  int l = t & 63;
  int w = t >> 6;
  int wm = w >> 1, wn = w & 1;
  int lr = l & 15, lh = l >> 4;
  long m0 = (long)blockIdx.y * 128, n0 = (long)blockIdx.x * 128;

  const unsigned short* Ag = A + (m0 + (t >> 2)) * K + (t & 3) * 8;
  const unsigned short* Bg = B + (n0 + (t >> 2)) * K + (t & 3) * 8;

  f32x4 acc[4][4];
  #pragma unroll
  for (int i = 0; i < 4; i++)
    #pragma unroll
    for (int j = 0; j < 4; j++)
      acc[i][j] = (f32x4){0.f, 0.f, 0.f, 0.f};

#define STAGE(buf, k0) do { \
    gload16(Ag + (k0), As + (buf) * 4096 + t * 8); \
    gload16(Ag + 64 * K + (k0), As + (buf) * 4096 + 2048 + t * 8); \
    gload16(Bg + (k0), Bs + (buf) * 4096 + t * 8); \
    gload16(Bg + 64 * K + (k0), Bs + (buf) * 4096 + 2048 + t * 8); \
  } while (0)

  int T = K >> 5;  // #K-tiles (>= 2)
  STAGE(0, 0);
  STAGE(1, 32);
  asm volatile("s_waitcnt vmcnt(4)" ::: "memory");  // tile 0 resident, tile 1 in flight
  __builtin_amdgcn_s_barrier();

  int bi = 0;
  for (int ti = 0; ti < T; ti++) {
    if (ti + 2 < T) STAGE((bi + 2) % 3, (ti + 2) * 32);
    const unsigned short* Ab = As + bi * 4096;
    const unsigned short* Bb = Bs + bi * 4096;
    half8 a[4], b[4];
    #pragma unroll
    for (int mf = 0; mf < 4; mf++)
      a[mf] = *(const half8*)&Ab[(wm * 64 + mf * 16 + lr) * 32 + lh * 8];
    #pragma unroll
    for (int nf = 0; nf < 4; nf++)
      b[nf] = *(const half8*)&Bb[(wn * 64 + nf * 16 + lr) * 32 + lh * 8];
    #pragma unroll
    for (int mf = 0; mf < 4; mf++)
      #pragma unroll
      for (int nf = 0; nf < 4; nf++)
        acc[mf][nf] = __builtin_amdgcn_mfma_f32_16x16x32_f16(a[mf], b[nf], acc[mf][nf], 0, 0, 0);
    // next tile must be resident after this barrier; tile ti+2 (4 loads) may stay in flight
    if (ti + 2 < T) asm volatile("s_waitcnt vmcnt(4)" ::: "memory");
    else            asm volatile("s_waitcnt vmcnt(0)" ::: "memory");
    __builtin_amdgcn_s_barrier();
    bi = bi == 2 ? 0 : bi + 1;
  }
#undef STAGE

  #pragma unroll
  for (int mf = 0; mf < 4; mf++)
    #pragma unroll
    for (int nf = 0; nf < 4; nf++)
      #pragma unroll
      for (int i = 0; i < 4; i++)
        C[(m0 + wm * 64 + mf * 16 + lh * 4 + i) * N + n0 + wn * 64 + nf * 16 + lr] = acc[mf][nf][i];
}

// ---------------- RoPE; Q additionally scaled by 1/sqrt(64)*log2(e) (folded, exact fp32) ----------------
__global__ void k_rope(const float* __restrict__ QKV, const float* __restrict__ fc,
                       const float* __restrict__ fs, unsigned short* __restrict__ Qr,
                       unsigned short* __restrict__ Kr) {
  const float SC = 0.125f * 1.44269504f;
  int s = blockIdx.x;
  for (int p = threadIdx.x; p < 1280; p += 256) {
    int col = p * 2;
    float t0 = QKV[(long)s * 3072 + col];
    float t1 = QKV[(long)s * 3072 + col + 1];
    if (col < 2048) {
      int j = (col & 63) >> 1;
      float c = fc[s * 32 + j] * SC, sn = fs[s * 32 + j] * SC;
      Qr[(long)s * 2048 + col] = f2h(t0 * c - t1 * sn);
      Qr[(long)s * 2048 + col + 1] = f2h(t0 * sn + t1 * c);
    } else {
      int cc = col - 2048;
      int hk = cc >> 6, d = cc & 63, j = d >> 1;
      float c = fc[s * 32 + j], sn = fs[s * 32 + j];
      Kr[((long)hk * SEQ + s) * 64 + d] = f2h(t0 * c - t1 * sn);
      Kr[((long)hk * SEQ + s) * 64 + d + 1] = f2h(t0 * sn + t1 * c);
    }
  }
}

// ---------------- causal GQA flash attention ----------------
// swapped-QK^T, 1 wave / 32 q-rows, K/V double-buffer prefetch, diag peeled, defer-rescale.
struct AttnState {
  f32x4 O[2][4];
  float mrun[2], lrun[2];
};

template <bool DIAG>
static __device__ __forceinline__ void attn_tile(
    int lr, int lh, const half8 (&Kf)[2][2], const half8 (&Vf)[4],
    const half8 (&Qf)[2][2], AttnState& st, unsigned short* Pq) {
  f32x4 St[2][2];
  #pragma unroll
  for (int n = 0; n < 2; n++)
    #pragma unroll
    for (int m = 0; m < 2; m++)
      St[n][m] = (f32x4){0.f, 0.f, 0.f, 0.f};
  #pragma unroll
  for (int n = 0; n < 2; n++)
    #pragma unroll
    for (int m = 0; m < 2; m++)
      #pragma unroll
      for (int kk = 0; kk < 2; kk++)
        St[n][m] = __builtin_amdgcn_mfma_f32_16x16x32_f16(Kf[n][kk], Qf[m][kk], St[n][m], 0, 0, 0);

  float fac[2];
  bool resc[2];
  #pragma unroll
  for (int m = 0; m < 2; m++) {
    float s[2][4];
    float mx = -1e30f;
    #pragma unroll
    for (int n = 0; n < 2; n++)
      #pragma unroll
      for (int i = 0; i < 4; i++) {
        float v = St[n][m][i];
        if (DIAG && (16 * n + 4 * lh + i > 16 * m + lr)) v = -1e30f;
        s[n][i] = v;
        mx = fmaxf(mx, v);
      }
    mx = fmaxf(mx, __shfl_xor(mx, 16));
    mx = fmaxf(mx, __shfl_xor(mx, 32));
    float nm;
    if (__ballot(mx > st.mrun[m] + 8.0f)) {  // wave-uniform: rescale path
      nm = fmaxf(st.mrun[m], mx);
      fac[m] = __builtin_exp2f(st.mrun[m] - nm);
      st.mrun[m] = nm;
      resc[m] = true;
    } else {  // defer-max skip path (T13): keep old max, P bounded by 2^8
      nm = st.mrun[m];
      resc[m] = false;
    }
    float ts = 0.f;
    float p[2][4];
    #pragma unroll
    for (int n = 0; n < 2; n++)
      #pragma unroll
      for (int i = 0; i < 4; i++) {
        p[n][i] = __builtin_exp2f(s[n][i] - nm);
        ts += p[n][i];
      }
    ts += __shfl_xor(ts, 16);
    ts += __shfl_xor(ts, 32);
    st.lrun[m] = (resc[m] ? st.lrun[m] * fac[m] : st.lrun[m]) + ts;

    #pragma unroll
    for (int n = 0; n < 2; n++) {
      uint2 val;
      val.x = pkh2(p[n][0], p[n][1]);
      val.y = pkh2(p[n][2], p[n][3]);
      *(uint2*)&Pq[(16 * m + lr) * 40 + 16 * n + 4 * lh] = val;
    }
  }

  #pragma unroll
  for (int m = 0; m < 2; m++)
    if (resc[m]) {
      #pragma unroll
      for (int i = 0; i < 4; i++) {
        float fi = __shfl(fac[m], 4 * lh + i);
        #pragma unroll
        for (int n = 0; n < 4; n++)
          st.O[m][n][i] *= fi;
      }
    }

  asm volatile("" ::: "memory");  // order ds_write before ds_read (same wave)

  half8 Pf[2];
  #pragma unroll
  for (int m = 0; m < 2; m++)
    Pf[m] = *(const half8*)&Pq[(16 * m + lr) * 40 + lh * 8];

  #pragma unroll
  for (int m = 0; m < 2; m++)
    #pragma unroll
    for (int nf = 0; nf < 4; nf++)
      st.O[m][nf] = __builtin_amdgcn_mfma_f32_16x16x32_f16(Pf[m], Vf[nf], st.O[m][nf], 0, 0, 0);
}

static __device__ __forceinline__ void loadKV(const unsigned short* Kh, const unsigned short* Vh,
                                              int t0, int lr, int lh,
                                              half8 (&Kf)[2][2], half8 (&Vf)[4]) {
  #pragma unroll
  for (int n = 0; n < 2; n++)
    #pragma unroll
    for (int kk = 0; kk < 2; kk++)
      Kf[n][kk] = *(const half8*)&Kh[(long)(t0 + n * 16 + lr) * 64 + kk * 32 + lh * 8];
  #pragma unroll
  for (int nf = 0; nf < 4; nf++)
    Vf[nf] = *(const half8*)&Vh[(long)(nf * 16 + lr) * SEQ + t0 + lh * 8];
}

__global__ __launch_bounds__(64) void k_attn(const unsigned short* __restrict__ Qr,
                                             const unsigned short* __restrict__ Kr,
                                             const unsigned short* __restrict__ Vt,
                                             unsigned short* __restrict__ AO) {
  __shared__ unsigned short Pq[32 * 40];
  int l = threadIdx.x;
  int lr = l & 15, lh = l >> 4;
  int h = blockIdx.x, hkv = h >> 2;
  int q0 = (gridDim.y - 1 - blockIdx.y) * 32;  // longest blocks dispatch first

  half8 Qf[2][2];
  #pragma unroll
  for (int m = 0; m < 2; m++)
    #pragma unroll
    for (int kk = 0; kk < 2; kk++)
      Qf[m][kk] = *(const half8*)&Qr[(long)(q0 + m * 16 + lr) * 2048 + h * 64 + kk * 32 + lh * 8];

  AttnState st;
  #pragma unroll
  for (int m = 0; m < 2; m++) {
    #pragma unroll
    for (int n = 0; n < 4; n++)
      st.O[m][n] = (f32x4){0.f, 0.f, 0.f, 0.f};
    st.mrun[m] = -1e30f;
    st.lrun[m] = 0.f;
  }

  const unsigned short* Kh = Kr + (long)hkv * SEQ * 64;
  const unsigned short* Vh = Vt + (long)hkv * 64 * SEQ;

  int nt = q0 >> 5;  // non-diag tile count
  half8 Ka[2][2], Va[4], Kb[2][2], Vb[4];
  loadKV(Kh, Vh, 0, lr, lh, Ka, Va);  // tile 0 (diag iff nt==0)

  int t = 0;
  while (t + 1 < nt) {
    loadKV(Kh, Vh, (t + 1) * 32, lr, lh, Kb, Vb);
    attn_tile<false>(lr, lh, Ka, Va, Qf, st, Pq);
    if (t + 2 < nt) loadKV(Kh, Vh, (t + 2) * 32, lr, lh, Ka, Va);
    else            loadKV(Kh, Vh, q0, lr, lh, Ka, Va);  // prefetch diag
    attn_tile<false>(lr, lh, Kb, Vb, Qf, st, Pq);
    t += 2;
  }
  if (nt == 0) {
    attn_tile<true>(lr, lh, Ka, Va, Qf, st, Pq);
  } else if (t < nt) {  // odd nt: one non-diag left in Ka
    loadKV(Kh, Vh, q0, lr, lh, Kb, Vb);
    attn_tile<false>(lr, lh, Ka, Va, Qf, st, Pq);
    attn_tile<true>(lr, lh, Kb, Vb, Qf, st, Pq);
  } else {  // even nt>0: diag prefetched into Ka
    attn_tile<true>(lr, lh, Ka, Va, Qf, st, Pq);
  }

  #pragma unroll
  for (int m = 0; m < 2; m++) {
    float rinv = 1.f / st.lrun[m];
    #pragma unroll
    for (int i = 0; i < 4; i++) {
      float vi = __shfl(rinv, 4 * lh + i);
      #pragma unroll
      for (int n = 0; n < 4; n++)
        AO[(long)(q0 + m * 16 + lh * 4 + i) * 2048 + h * 64 + n * 16 + lr] = f2h(st.O[m][n][i] * vi);
    }
  }
}

extern "C" void kernel_launch(void* const* d_in, const int* in_sizes, int n_in,
                              void* d_out, int out_size, void* d_ws, size_t ws_size,
                              hipStream_t stream) {
  const float* x  = (const float*)d_in[0];
  const float* fc = (const float*)d_in[1];
  const float* fs = (const float*)d_in[2];
  const float* Wq = (const float*)d_in[4];
  const float* Wk = (const float*)d_in[5];
  const float* Wv = (const float*)d_in[6];
  const float* Wo = (const float*)d_in[7];
  float* out = (float*)d_out;

  char* ws = (char*)d_ws;
  unsigned short* xb  = (unsigned short*)(ws);                  // 8 MB (reused as AO later)
  unsigned short* WT  = (unsigned short*)(ws + (8l  << 20));    // 12 MB  [3072][2048] fp16
  unsigned short* WoT = (unsigned short*)(ws + (20l << 20));    // 8 MB   [2048][2048] fp16
  float*          QKV = (float*)(ws + (28l << 20));             // 24 MB  [2048][3072] fp32
  unsigned short* Qr  = (unsigned short*)(ws + (52l << 20));    // 8 MB
  unsigned short* Kr  = (unsigned short*)(ws + (60l << 20));    // 2 MB
  unsigned short* Vt  = (unsigned short*)(ws + (62l << 20));    // 2 MB
  unsigned short* AO  = xb;                                     // overlay: xb dead after QKV GEMM

  dim3 tb(32, 8);
  k_cvt<<<4096, 256, 0, stream>>>(x, xb, 2048 * 2048);
  k_tcvt<<<dim3(64, 64, 1), tb, 0, stream>>>(Wq, WT, 2048, 2048, 2048, 0, 0);
  k_tcvt<<<dim3(16, 64, 1), tb, 0, stream>>>(Wk, WT + 2048l * 2048, 2048, 512, 512, 0, 0);
  k_tcvt<<<dim3(16, 64, 1), tb, 0, stream>>>(Wv, WT + 2560l * 2048, 2048, 512, 512, 0, 0);
  k_tcvt<<<dim3(64, 64, 1), tb, 0, stream>>>(Wo, WoT, 2048, 2048, 2048, 0, 0);

  k_gemm<<<dim3(24, 16), 256, 0, stream>>>(xb, WT, QKV, 2048, 3072, 2048);

  k_rope<<<2048, 256, 0, stream>>>(QKV, fc, fs, Qr, Kr);
  k_tcvt<<<dim3(2, 64, 8), tb, 0, stream>>>(QKV + 2560, Vt, 2048, 64, 3072, 64, 64l * 2048);

  k_attn<<<dim3(32, 64), 64, 0, stream>>>(Qr, Kr, Vt, AO);

  k_gemm<<<dim3(16, 16), 256, 0, stream>>>(AO, WoT, out, 2048, 2048, 2048);
}

// Round 5
// 194.934 us; speedup vs baseline: 1.4354x; 1.0973x over previous
//
#include <hip/hip_runtime.h>

#define SEQ 2048
#define DMODEL 2048

typedef __attribute__((ext_vector_type(8))) _Float16 half8;
typedef __attribute__((ext_vector_type(4))) float f32x4;

typedef const __attribute__((address_space(1))) void* gptr_t;
typedef __attribute__((address_space(3))) void* lptr_t;

static __device__ __forceinline__ void gload16(const void* g, void* l) {
  __builtin_amdgcn_global_load_lds((gptr_t)g, (lptr_t)l, 16, 0, 0);
}

static __device__ __forceinline__ unsigned short f2h(float f) {
  _Float16 h = (_Float16)f;
  union { _Float16 h; unsigned short u; } v; v.h = h;
  return v.u;
}

static __device__ __forceinline__ unsigned int pkh2(float a, float b) {
  union { __fp16 __attribute__((ext_vector_type(2))) h; unsigned int u; } v;
  v.h = __builtin_amdgcn_cvt_pkrtz(a, b);
  return v.u;
}

// ---------------- elementwise fp32 -> fp16 ----------------
__global__ void k_cvt(const float* __restrict__ in, unsigned short* __restrict__ out, int n) {
  int i = (blockIdx.x * 256 + threadIdx.x) * 4;
  if (i >= n) return;
  float4 v = *(const float4*)(in + i);
  ushort4 o;
  o.x = f2h(v.x); o.y = f2h(v.y); o.z = f2h(v.z); o.w = f2h(v.w);
  *(ushort4*)(out + i) = o;
}

// ---------------- tiled transpose + convert: in fp32 [K][N] -> out fp16 [N][K] ----------------
__global__ void k_tcvt(const float* __restrict__ in, unsigned short* __restrict__ out,
                       int K, int N, int ldin, long inb, long outb) {
  in += (long)blockIdx.z * inb;
  out += (long)blockIdx.z * outb;
  __shared__ float tile[32][33];
  int n0 = blockIdx.x * 32, k0 = blockIdx.y * 32;
  int tx = threadIdx.x, ty = threadIdx.y;  // 32 x 8
  #pragma unroll
  for (int j = ty; j < 32; j += 8)
    tile[j][tx] = in[(long)(k0 + j) * ldin + n0 + tx];
  __syncthreads();
  #pragma unroll
  for (int j = ty; j < 32; j += 8)
    out[(long)(n0 + j) * K + k0 + tx] = f2h(tile[tx][j]);
}

// ---------------- GEMM: C[M][N] fp32 = A[M][K] fp16 * Bt[N][K] fp16 ----------------
// 128x128 tile, BK=32, 8 waves (4m x 2n, 32x64 each), depth-2 ring, counted vmcnt.
__global__ __launch_bounds__(512) void k_gemm(const unsigned short* __restrict__ A,
                                              const unsigned short* __restrict__ B,
                                              float* __restrict__ C, int M, int N, int K) {
  __shared__ unsigned short As[3 * 4096];
  __shared__ unsigned short Bs[3 * 4096];
  int t = threadIdx.x;
  int l = t & 63;
  int w = t >> 6;
  int wm = w >> 1, wn = w & 1;   // 4 x 2 wave grid; wave tile 32(m) x 64(n)
  int lr = l & 15, lh = l >> 4;
  long m0 = (long)blockIdx.y * 128, n0 = (long)blockIdx.x * 128;

  const unsigned short* Ag = A + (m0 + (t >> 2)) * K + (t & 3) * 8;
  const unsigned short* Bg = B + (n0 + (t >> 2)) * K + (t & 3) * 8;

  f32x4 acc[2][4];
  #pragma unroll
  for (int i = 0; i < 2; i++)
    #pragma unroll
    for (int j = 0; j < 4; j++)
      acc[i][j] = (f32x4){0.f, 0.f, 0.f, 0.f};

#define STAGE(buf, k0) do { \
    gload16(Ag + (k0), As + (buf) * 4096 + t * 8); \
    gload16(Bg + (k0), Bs + (buf) * 4096 + t * 8); \
  } while (0)

  int T = K >> 5;  // #K-tiles (>= 2)
  STAGE(0, 0);
  STAGE(1, 32);
  asm volatile("s_waitcnt vmcnt(2)" ::: "memory");  // tile 0 resident, tile 1 in flight
  __builtin_amdgcn_s_barrier();

  int bi = 0;
  for (int ti = 0; ti < T; ti++) {
    if (ti + 2 < T) STAGE((bi + 2) % 3, (ti + 2) * 32);
    const unsigned short* Ab = As + bi * 4096;
    const unsigned short* Bb = Bs + bi * 4096;
    half8 a[2], b[4];
    #pragma unroll
    for (int mf = 0; mf < 2; mf++)
      a[mf] = *(const half8*)&Ab[(wm * 32 + mf * 16 + lr) * 32 + lh * 8];
    #pragma unroll
    for (int nf = 0; nf < 4; nf++)
      b[nf] = *(const half8*)&Bb[(wn * 64 + nf * 16 + lr) * 32 + lh * 8];
    #pragma unroll
    for (int mf = 0; mf < 2; mf++)
      #pragma unroll
      for (int nf = 0; nf < 4; nf++)
        acc[mf][nf] = __builtin_amdgcn_mfma_f32_16x16x32_f16(a[mf], b[nf], acc[mf][nf], 0, 0, 0);
    if (ti + 2 < T) asm volatile("s_waitcnt vmcnt(2)" ::: "memory");
    else            asm volatile("s_waitcnt vmcnt(0)" ::: "memory");
    __builtin_amdgcn_s_barrier();
    bi = bi == 2 ? 0 : bi + 1;
  }
#undef STAGE

  #pragma unroll
  for (int mf = 0; mf < 2; mf++)
    #pragma unroll
    for (int nf = 0; nf < 4; nf++)
      #pragma unroll
      for (int i = 0; i < 4; i++)
        C[(m0 + wm * 32 + mf * 16 + lh * 4 + i) * N + n0 + wn * 64 + nf * 16 + lr] = acc[mf][nf][i];
}

// ---------------- RoPE; Q additionally scaled by 1/sqrt(64)*log2(e) (folded, exact fp32) ----------------
__global__ void k_rope(const float* __restrict__ QKV, const float* __restrict__ fc,
                       const float* __restrict__ fs, unsigned short* __restrict__ Qr,
                       unsigned short* __restrict__ Kr) {
  const float SC = 0.125f * 1.44269504f;
  int s = blockIdx.x;
  for (int p = threadIdx.x; p < 1280; p += 256) {
    int col = p * 2;
    float t0 = QKV[(long)s * 3072 + col];
    float t1 = QKV[(long)s * 3072 + col + 1];
    if (col < 2048) {
      int j = (col & 63) >> 1;
      float c = fc[s * 32 + j] * SC, sn = fs[s * 32 + j] * SC;
      Qr[(long)s * 2048 + col] = f2h(t0 * c - t1 * sn);
      Qr[(long)s * 2048 + col + 1] = f2h(t0 * sn + t1 * c);
    } else {
      int cc = col - 2048;
      int hk = cc >> 6, d = cc & 63, j = d >> 1;
      float c = fc[s * 32 + j], sn = fs[s * 32 + j];
      Kr[((long)hk * SEQ + s) * 64 + d] = f2h(t0 * c - t1 * sn);
      Kr[((long)hk * SEQ + s) * 64 + d + 1] = f2h(t0 * sn + t1 * c);
    }
  }
}

// ---------------- causal GQA flash attention ----------------
// swapped-QK^T, 2 waves/block split-KV (even/odd tiles), LDS merge, defer-rescale.
struct AttnState {
  f32x4 O[2][4];
  float mrun[2], lrun[2];
};

template <bool DIAG>
static __device__ __forceinline__ void attn_tile(
    int lr, int lh, const half8 (&Kf)[2][2], const half8 (&Vf)[4],
    const half8 (&Qf)[2][2], AttnState& st, unsigned short* Pq) {
  f32x4 St[2][2];
  #pragma unroll
  for (int n = 0; n < 2; n++)
    #pragma unroll
    for (int m = 0; m < 2; m++)
      St[n][m] = (f32x4){0.f, 0.f, 0.f, 0.f};
  #pragma unroll
  for (int n = 0; n < 2; n++)
    #pragma unroll
    for (int m = 0; m < 2; m++)
      #pragma unroll
      for (int kk = 0; kk < 2; kk++)
        St[n][m] = __builtin_amdgcn_mfma_f32_16x16x32_f16(Kf[n][kk], Qf[m][kk], St[n][m], 0, 0, 0);

  float fac[2];
  bool resc[2];
  #pragma unroll
  for (int m = 0; m < 2; m++) {
    float s[2][4];
    float mx = -1e30f;
    #pragma unroll
    for (int n = 0; n < 2; n++)
      #pragma unroll
      for (int i = 0; i < 4; i++) {
        float v = St[n][m][i];
        if (DIAG && (16 * n + 4 * lh + i > 16 * m + lr)) v = -1e30f;
        s[n][i] = v;
        mx = fmaxf(mx, v);
      }
    mx = fmaxf(mx, __shfl_xor(mx, 16));
    mx = fmaxf(mx, __shfl_xor(mx, 32));
    float nm;
    if (__ballot(mx > st.mrun[m] + 8.0f)) {  // wave-uniform rescale path
      nm = fmaxf(st.mrun[m], mx);
      fac[m] = __builtin_exp2f(st.mrun[m] - nm);
      st.mrun[m] = nm;
      resc[m] = true;
    } else {  // defer-max (T13): keep old max, P bounded by 2^8
      nm = st.mrun[m];
      resc[m] = false;
    }
    float ts = 0.f;
    float p[2][4];
    #pragma unroll
    for (int n = 0; n < 2; n++)
      #pragma unroll
      for (int i = 0; i < 4; i++) {
        p[n][i] = __builtin_exp2f(s[n][i] - nm);
        ts += p[n][i];
      }
    ts += __shfl_xor(ts, 16);
    ts += __shfl_xor(ts, 32);
    st.lrun[m] = (resc[m] ? st.lrun[m] * fac[m] : st.lrun[m]) + ts;

    #pragma unroll
    for (int n = 0; n < 2; n++) {
      uint2 val;
      val.x = pkh2(p[n][0], p[n][1]);
      val.y = pkh2(p[n][2], p[n][3]);
      *(uint2*)&Pq[(16 * m + lr) * 40 + 16 * n + 4 * lh] = val;
    }
  }

  #pragma unroll
  for (int m = 0; m < 2; m++)
    if (resc[m]) {
      #pragma unroll
      for (int i = 0; i < 4; i++) {
        float fi = __shfl(fac[m], 4 * lh + i);
        #pragma unroll
        for (int n = 0; n < 4; n++)
          st.O[m][n][i] *= fi;
      }
    }

  asm volatile("" ::: "memory");  // order ds_write before ds_read (same wave)

  half8 Pf[2];
  #pragma unroll
  for (int m = 0; m < 2; m++)
    Pf[m] = *(const half8*)&Pq[(16 * m + lr) * 40 + lh * 8];

  #pragma unroll
  for (int m = 0; m < 2; m++)
    #pragma unroll
    for (int nf = 0; nf < 4; nf++)
      st.O[m][nf] = __builtin_amdgcn_mfma_f32_16x16x32_f16(Pf[m], Vf[nf], st.O[m][nf], 0, 0, 0);
}

static __device__ __forceinline__ void loadKV(const unsigned short* Kh, const unsigned short* Vh,
                                              int t0, int lr, int lh,
                                              half8 (&Kf)[2][2], half8 (&Vf)[4]) {
  #pragma unroll
  for (int n = 0; n < 2; n++)
    #pragma unroll
    for (int kk = 0; kk < 2; kk++)
      Kf[n][kk] = *(const half8*)&Kh[(long)(t0 + n * 16 + lr) * 64 + kk * 32 + lh * 8];
  #pragma unroll
  for (int nf = 0; nf < 4; nf++)
    Vf[nf] = *(const half8*)&Vh[(long)(nf * 16 + lr) * SEQ + t0 + lh * 8];
}

// grid (32 heads, 64 q-tiles rev), block 128 (2 waves). Wave w handles KV-tiles idx % 2 == w.
__global__ __launch_bounds__(128) void k_attn(const unsigned short* __restrict__ Qr,
                                              const unsigned short* __restrict__ Kr,
                                              const unsigned short* __restrict__ Vt,
                                              unsigned short* __restrict__ AO) {
  __shared__ float smem[2304];  // 9216 B: 2x Pq (2560 B) during loop; 64x36 f32 merge buffer after
  int tt = threadIdx.x;
  int wid = tt >> 6, l = tt & 63;
  int lr = l & 15, lh = l >> 4;
  int h = blockIdx.x, hkv = h >> 2;
  int q0 = (gridDim.y - 1 - blockIdx.y) * 32;  // longest blocks dispatch first
  unsigned short* Pq = (unsigned short*)smem + wid * 1280;

  half8 Qf[2][2];
  #pragma unroll
  for (int m = 0; m < 2; m++)
    #pragma unroll
    for (int kk = 0; kk < 2; kk++)
      Qf[m][kk] = *(const half8*)&Qr[(long)(q0 + m * 16 + lr) * 2048 + h * 64 + kk * 32 + lh * 8];

  AttnState st;
  #pragma unroll
  for (int m = 0; m < 2; m++) {
    #pragma unroll
    for (int n = 0; n < 4; n++)
      st.O[m][n] = (f32x4){0.f, 0.f, 0.f, 0.f};
    st.mrun[m] = -1e30f;
    st.lrun[m] = 0.f;
  }

  const unsigned short* Kh = Kr + (long)hkv * SEQ * 64;
  const unsigned short* Vh = Vt + (long)hkv * 64 * SEQ;

  int di = q0 >> 5;  // diag tile index; wave w owns tiles w, w+2, ..., <= di
  half8 Ka[2][2], Va[4], Kb[2][2], Vb[4];
  int idx = wid;
  if (idx <= di) {
    loadKV(Kh, Vh, idx * 32, lr, lh, Ka, Va);
    while (idx + 2 <= di) {
      loadKV(Kh, Vh, (idx + 2) * 32, lr, lh, Kb, Vb);
      attn_tile<false>(lr, lh, Ka, Va, Qf, st, Pq);
      idx += 2;
      if (idx + 2 <= di) {
        loadKV(Kh, Vh, (idx + 2) * 32, lr, lh, Ka, Va);
        attn_tile<false>(lr, lh, Kb, Vb, Qf, st, Pq);
        idx += 2;
      } else {
        // Kb is the last tile for this wave
        if (idx == di) attn_tile<true>(lr, lh, Kb, Vb, Qf, st, Pq);
        else           attn_tile<false>(lr, lh, Kb, Vb, Qf, st, Pq);
        idx += 2;  // mark consumed
      }
    }
    if (idx <= di) {  // last tile still in Ka
      if (idx == di) attn_tile<true>(lr, lh, Ka, Va, Qf, st, Pq);
      else           attn_tile<false>(lr, lh, Ka, Va, Qf, st, Pq);
    }
  }

  // ---- merge wave1 into wave0 via LDS ----
  __syncthreads();  // all Pq traffic done
  if (wid == 1) {
    float* c = smem + l * 36;
    #pragma unroll
    for (int m = 0; m < 2; m++)
      #pragma unroll
      for (int n = 0; n < 4; n++)
        #pragma unroll
        for (int i = 0; i < 4; i++)
          c[m * 16 + n * 4 + i] = st.O[m][n][i];
    c[32] = st.mrun[0]; c[33] = st.mrun[1];
    c[34] = st.lrun[0]; c[35] = st.lrun[1];
  }
  __syncthreads();
  if (wid == 0) {
    const float* c = smem + l * 36;
    float g0[2], g1[2];
    #pragma unroll
    for (int m = 0; m < 2; m++) {
      float m1 = c[32 + m], l1 = c[34 + m];
      float nm = fmaxf(st.mrun[m], m1);
      float f0 = __builtin_exp2f(st.mrun[m] - nm);
      float f1 = __builtin_exp2f(m1 - nm);
      float lt = st.lrun[m] * f0 + l1 * f1;
      float ri = 1.f / lt;
      g0[m] = f0 * ri;
      g1[m] = f1 * ri;
    }
    #pragma unroll
    for (int m = 0; m < 2; m++)
      #pragma unroll
      for (int i = 0; i < 4; i++) {
        float gi0 = __shfl(g0[m], 4 * lh + i);
        float gi1 = __shfl(g1[m], 4 * lh + i);
        #pragma unroll
        for (int n = 0; n < 4; n++) {
          float o1 = c[m * 16 + n * 4 + i];
          AO[(long)(q0 + m * 16 + lh * 4 + i) * 2048 + h * 64 + n * 16 + lr] =
              f2h(st.O[m][n][i] * gi0 + o1 * gi1);
        }
      }
  }
}

extern "C" void kernel_launch(void* const* d_in, const int* in_sizes, int n_in,
                              void* d_out, int out_size, void* d_ws, size_t ws_size,
                              hipStream_t stream) {
  const float* x  = (const float*)d_in[0];
  const float* fc = (const float*)d_in[1];
  const float* fs = (const float*)d_in[2];
  const float* Wq = (const float*)d_in[4];
  const float* Wk = (const float*)d_in[5];
  const float* Wv = (const float*)d_in[6];
  const float* Wo = (const float*)d_in[7];
  float* out = (float*)d_out;

  char* ws = (char*)d_ws;
  unsigned short* xb  = (unsigned short*)(ws);                  // 8 MB (reused as AO later)
  unsigned short* WT  = (unsigned short*)(ws + (8l  << 20));    // 12 MB  [3072][2048] fp16
  unsigned short* WoT = (unsigned short*)(ws + (20l << 20));    // 8 MB   [2048][2048] fp16
  float*          QKV = (float*)(ws + (28l << 20));             // 24 MB  [2048][3072] fp32
  unsigned short* Qr  = (unsigned short*)(ws + (52l << 20));    // 8 MB
  unsigned short* Kr  = (unsigned short*)(ws + (60l << 20));    // 2 MB
  unsigned short* Vt  = (unsigned short*)(ws + (62l << 20));    // 2 MB
  unsigned short* AO  = xb;                                     // overlay: xb dead after QKV GEMM

  dim3 tb(32, 8);
  k_cvt<<<4096, 256, 0, stream>>>(x, xb, 2048 * 2048);
  k_tcvt<<<dim3(64, 64, 1), tb, 0, stream>>>(Wq, WT, 2048, 2048, 2048, 0, 0);
  k_tcvt<<<dim3(16, 64, 1), tb, 0, stream>>>(Wk, WT + 2048l * 2048, 2048, 512, 512, 0, 0);
  k_tcvt<<<dim3(16, 64, 1), tb, 0, stream>>>(Wv, WT + 2560l * 2048, 2048, 512, 512, 0, 0);
  k_tcvt<<<dim3(64, 64, 1), tb, 0, stream>>>(Wo, WoT, 2048, 2048, 2048, 0, 0);

  k_gemm<<<dim3(24, 16), 512, 0, stream>>>(xb, WT, QKV, 2048, 3072, 2048);

  k_rope<<<2048, 256, 0, stream>>>(QKV, fc, fs, Qr, Kr);
  k_tcvt<<<dim3(2, 64, 8), tb, 0, stream>>>(QKV + 2560, Vt, 2048, 64, 3072, 64, 64l * 2048);

  k_attn<<<dim3(32, 64), 128, 0, stream>>>(Qr, Kr, Vt, AO);

  k_gemm<<<dim3(16, 16), 512, 0, stream>>>(AO, WoT, out, 2048, 2048, 2048);
}